// Round 13
// baseline (202.782 us; speedup 1.0000x reference)
//
#include <hip/hip_runtime.h>
#include <hip/hip_bf16.h>

// Problem constants: B=4, L=2048, H=8, D=64, SAMPLE_K=N_TOP=40
#define BB 4
#define LL 2048
#define HH 8
#define DD 64
#define SK 40
#define NT 40
#define CH 256              // keys per attn chunk
#define NCH (LL / CH)       // 8 chunks per (b,h)
#define QH 20               // queries per attn block (40 split in 2)

typedef float f4 __attribute__((ext_vector_type(4)));

// ---------------------------------------------------------------------------
// Kernel 1: M[bh][l] = max_s(q . k_{idx[l,s]}) - (sum_s q . k_{idx[l,s]}) / L
//
// Round 26. r12 spill root-cause: each IS carried a 64-bit "s"(pointer)
// operand -> 40 hoisted pointer pairs = 80 live SGPRs -> SGPR spill to VGPR
// -> VGPR spill to scratch (WRITE 80MB, FETCH doubled as scratch thrashed
// L2). Fix: 32-BIT ADDRESS STATE. One constant SGPR base (K + b*4MB), one
// constant VGPR lane offset; per sample the asm does
//   v_add_u32 vtmp, s_rowoff, v_laneoff ; global_load_dwordx4 R, vtmp, s[base]
// where s_rowoff = readlane(myidx<<11, k) is ONE 32-bit SGPR (40 total,
// fits the SGPR file). Live VGPRs ~45 << 128 cap -> no spill possible.
// Same half-row time phasing as r12 (phase p touches bytes [p*1KB,+1KB) of
// each sampled row; per-XCD live set 2.1MB < 4MB L2), depth-6 rolling
// pipeline, 4 FMA + 4 shfl_xor per sample, Q nontemporal, no LDS/barriers.
// ---------------------------------------------------------------------------
__global__ __launch_bounds__(256, 4) void compute_m_kernel(
        const float* __restrict__ Q, const float* __restrict__ K,
        const int* __restrict__ idx, float* __restrict__ M) {
    int blk = blockIdx.x;
    int x = blk & 7, g = blk >> 3;
    int b = x >> 1;                    // 2 XCDs per batch
    int lg = (g << 1) | (x & 1);       // l-group [0,512)
    int t = threadIdx.x;
    int lane = t & 63, w = t >> 6;
    int l = lg * 4 + w;                // this wave's l

    // Q fragments, identity map with the two row halves (nontemporal stream)
    const f4* q0p = (const f4*)(Q + ((size_t)b * LL + l) * 512 + lane * 4);
    const f4* q1p = (const f4*)(Q + ((size_t)b * LL + l) * 512 + 256 + lane * 4);
    f4 qf0 = __builtin_nontemporal_load(q0p);
    f4 qf1 = __builtin_nontemporal_load(q1p);

    // idx row: coalesced read by lanes 0..39; rb = row byte offset (32-bit)
    int myidx = 0;
    if (lane < SK) myidx = idx[(size_t)l * SK + lane];
    int rb = myidx << 11;              // idx * 2048 bytes

    const float* Kb8 = K + (size_t)b * LL * 512;   // constant SGPR base
    int voff0 = lane * 16;             // lane's 16B in half 0 (contiguous 1KB)
    int voff1 = lane * 16 + 1024;      // ... in half 1

    // Drain compiler-tracked loads (Q, idx) before the asm pipeline.
    asm volatile("" : "+v"(qf0), "+v"(qf1));

    f4 R0, R1, R2, R3, R4, R5;
    int vtmp;                          // address temp (reused; read at issue)

    #define IS(RV, k, VO) do {                                                  \
        int _rbk = __builtin_amdgcn_readlane(rb, (k));                          \
        asm volatile("v_add_u32 %0, %2, %3\n\t"                                 \
                     "global_load_dwordx4 %1, %0, %4"                           \
                     : "=&v"(vtmp), "=&v"(RV)                                   \
                     : "s"(_rbk), "v"(VO), "s"(Kb8));                           \
    } while (0)

    float mx0 = -INFINITY, sm0 = 0.0f, mx1 = -INFINITY, sm1 = 0.0f;

    #define CO(RV, QF, MX, SM, WAIT) do {                                       \
        asm volatile(WAIT : "+v"(RV));                                          \
        float p = QF.x*RV.x + QF.y*RV.y + QF.z*RV.z + QF.w*RV.w;                \
        p += __shfl_xor(p, 1, 64);                                              \
        p += __shfl_xor(p, 2, 64);                                              \
        p += __shfl_xor(p, 4, 64);                                              \
        p += __shfl_xor(p, 8, 64);                                              \
        MX = fmaxf(MX, p);                                                      \
        SM += p;                                                                \
    } while (0)

    #define STEP(RV, QF, MX, SM, NXT, VO)                                       \
        CO(RV, QF, MX, SM, "s_waitcnt vmcnt(5)"); IS(RV, NXT, VO)

    // ---------------- phase 0: first halves, heads 0-3 ----------------
    IS(R0, 0, voff0); IS(R1, 1, voff0); IS(R2, 2, voff0);
    IS(R3, 3, voff0); IS(R4, 4, voff0); IS(R5, 5, voff0);
    STEP(R0, qf0, mx0, sm0,  6, voff0); STEP(R1, qf0, mx0, sm0,  7, voff0);
    STEP(R2, qf0, mx0, sm0,  8, voff0); STEP(R3, qf0, mx0, sm0,  9, voff0);
    STEP(R4, qf0, mx0, sm0, 10, voff0); STEP(R5, qf0, mx0, sm0, 11, voff0);
    STEP(R0, qf0, mx0, sm0, 12, voff0); STEP(R1, qf0, mx0, sm0, 13, voff0);
    STEP(R2, qf0, mx0, sm0, 14, voff0); STEP(R3, qf0, mx0, sm0, 15, voff0);
    STEP(R4, qf0, mx0, sm0, 16, voff0); STEP(R5, qf0, mx0, sm0, 17, voff0);
    STEP(R0, qf0, mx0, sm0, 18, voff0); STEP(R1, qf0, mx0, sm0, 19, voff0);
    STEP(R2, qf0, mx0, sm0, 20, voff0); STEP(R3, qf0, mx0, sm0, 21, voff0);
    STEP(R4, qf0, mx0, sm0, 22, voff0); STEP(R5, qf0, mx0, sm0, 23, voff0);
    STEP(R0, qf0, mx0, sm0, 24, voff0); STEP(R1, qf0, mx0, sm0, 25, voff0);
    STEP(R2, qf0, mx0, sm0, 26, voff0); STEP(R3, qf0, mx0, sm0, 27, voff0);
    STEP(R4, qf0, mx0, sm0, 28, voff0); STEP(R5, qf0, mx0, sm0, 29, voff0);
    STEP(R0, qf0, mx0, sm0, 30, voff0); STEP(R1, qf0, mx0, sm0, 31, voff0);
    STEP(R2, qf0, mx0, sm0, 32, voff0); STEP(R3, qf0, mx0, sm0, 33, voff0);
    STEP(R4, qf0, mx0, sm0, 34, voff0); STEP(R5, qf0, mx0, sm0, 35, voff0);
    STEP(R0, qf0, mx0, sm0, 36, voff0); STEP(R1, qf0, mx0, sm0, 37, voff0);
    STEP(R2, qf0, mx0, sm0, 38, voff0); STEP(R3, qf0, mx0, sm0, 39, voff0);
    // drain: outstanding samples 34..39 in R4,R5,R0,R1,R2,R3
    CO(R4, qf0, mx0, sm0, "s_waitcnt vmcnt(5)");
    CO(R5, qf0, mx0, sm0, "s_waitcnt vmcnt(4)");
    CO(R0, qf0, mx0, sm0, "s_waitcnt vmcnt(3)");
    CO(R1, qf0, mx0, sm0, "s_waitcnt vmcnt(2)");
    CO(R2, qf0, mx0, sm0, "s_waitcnt vmcnt(1)");
    CO(R3, qf0, mx0, sm0, "s_waitcnt vmcnt(0)");

    // ---------------- phase 1: second halves, heads 4-7 ----------------
    IS(R0, 0, voff1); IS(R1, 1, voff1); IS(R2, 2, voff1);
    IS(R3, 3, voff1); IS(R4, 4, voff1); IS(R5, 5, voff1);
    STEP(R0, qf1, mx1, sm1,  6, voff1); STEP(R1, qf1, mx1, sm1,  7, voff1);
    STEP(R2, qf1, mx1, sm1,  8, voff1); STEP(R3, qf1, mx1, sm1,  9, voff1);
    STEP(R4, qf1, mx1, sm1, 10, voff1); STEP(R5, qf1, mx1, sm1, 11, voff1);
    STEP(R0, qf1, mx1, sm1, 12, voff1); STEP(R1, qf1, mx1, sm1, 13, voff1);
    STEP(R2, qf1, mx1, sm1, 14, voff1); STEP(R3, qf1, mx1, sm1, 15, voff1);
    STEP(R4, qf1, mx1, sm1, 16, voff1); STEP(R5, qf1, mx1, sm1, 17, voff1);
    STEP(R0, qf1, mx1, sm1, 18, voff1); STEP(R1, qf1, mx1, sm1, 19, voff1);
    STEP(R2, qf1, mx1, sm1, 20, voff1); STEP(R3, qf1, mx1, sm1, 21, voff1);
    STEP(R4, qf1, mx1, sm1, 22, voff1); STEP(R5, qf1, mx1, sm1, 23, voff1);
    STEP(R0, qf1, mx1, sm1, 24, voff1); STEP(R1, qf1, mx1, sm1, 25, voff1);
    STEP(R2, qf1, mx1, sm1, 26, voff1); STEP(R3, qf1, mx1, sm1, 27, voff1);
    STEP(R4, qf1, mx1, sm1, 28, voff1); STEP(R5, qf1, mx1, sm1, 29, voff1);
    STEP(R0, qf1, mx1, sm1, 30, voff1); STEP(R1, qf1, mx1, sm1, 31, voff1);
    STEP(R2, qf1, mx1, sm1, 32, voff1); STEP(R3, qf1, mx1, sm1, 33, voff1);
    STEP(R4, qf1, mx1, sm1, 34, voff1); STEP(R5, qf1, mx1, sm1, 35, voff1);
    STEP(R0, qf1, mx1, sm1, 36, voff1); STEP(R1, qf1, mx1, sm1, 37, voff1);
    STEP(R2, qf1, mx1, sm1, 38, voff1); STEP(R3, qf1, mx1, sm1, 39, voff1);
    CO(R4, qf1, mx1, sm1, "s_waitcnt vmcnt(5)");
    CO(R5, qf1, mx1, sm1, "s_waitcnt vmcnt(4)");
    CO(R0, qf1, mx1, sm1, "s_waitcnt vmcnt(3)");
    CO(R1, qf1, mx1, sm1, "s_waitcnt vmcnt(2)");
    CO(R2, qf1, mx1, sm1, "s_waitcnt vmcnt(1)");
    CO(R3, qf1, mx1, sm1, "s_waitcnt vmcnt(0)");
    #undef IS
    #undef CO
    #undef STEP

    // leaders (lane&15)==0: head lane>>4 from phase 0, head +4 from phase 1
    if ((lane & 15) == 0) {
        int h0 = lane >> 4;
        M[((size_t)b * HH + h0) * LL + l]     = mx0 - sm0 * (1.0f / (float)LL);
        M[((size_t)b * HH + h0 + 4) * LL + l] = mx1 - sm1 * (1.0f / (float)LL);
    }
}

// ---------------------------------------------------------------------------
// Kernel 2: top-40 per (b,h), lower index wins ties. Incremental argmax.
// ---------------------------------------------------------------------------
__global__ __launch_bounds__(256) void topk_kernel(const float* __restrict__ M,
                                                   int* __restrict__ topi) {
    __shared__ unsigned long long keys[LL];   // 16 KB
    __shared__ unsigned long long wmax[4];
    __shared__ int win;
    int bh = blockIdx.x;
    int t  = threadIdx.x;
    int lane = t & 63, w = t >> 6;

    unsigned long long kmax = 0ULL;
    #pragma unroll
    for (int j = 0; j < 8; ++j) {
        int i = t + 256 * j;
        unsigned int bits = __float_as_uint(M[(size_t)bh * LL + i]);
        bits = (bits & 0x80000000u) ? ~bits : (bits | 0x80000000u);
        unsigned long long k = ((unsigned long long)bits << 11)
                             | (unsigned int)(LL - 1 - i);
        keys[i] = k;
        if (k > kmax) kmax = k;
    }
    __syncthreads();

    for (int u = 0; u < NT; ++u) {
        unsigned long long k = kmax;
        #pragma unroll
        for (int off = 32; off >= 1; off >>= 1) {
            unsigned long long o = __shfl_xor(k, off, 64);
            if (o > k) k = o;
        }
        if (lane == 0) wmax[w] = k;
        __syncthreads();
        if (t == 0) {
            unsigned long long k0 = wmax[0];
            if (wmax[1] > k0) k0 = wmax[1];
            if (wmax[2] > k0) k0 = wmax[2];
            if (wmax[3] > k0) k0 = wmax[3];
            int i = (LL - 1) - (int)(k0 & 0x7FF);
            topi[bh * NT + u] = i;
            keys[i] = 0ULL;
            win = i;
        }
        __syncthreads();
        if ((win & 255) == t) {          // only the owner rescans
            kmax = 0ULL;
            #pragma unroll
            for (int j = 0; j < 8; ++j) {
                unsigned long long kk = keys[t + 256 * j];
                if (kk > kmax) kmax = kk;
            }
        }
    }
}

// ---------------------------------------------------------------------------
// Kernel 3: flash-chunked attention, query-split.
// __launch_bounds__(256,3) keeps kreg/vcol in registers (round 7 spill fix).
// (m,l) packed float2 store (round 8 granule-waste fix).
// ---------------------------------------------------------------------------
__global__ __launch_bounds__(256, 3) void attn_kernel(
        const float* __restrict__ Q, const float* __restrict__ K,
        const float* __restrict__ V, const int* __restrict__ topi,
        float2* __restrict__ pml, float* __restrict__ po) {
    __shared__ float  qs[QH][DD];        //  5120 B
    __shared__ float4 e4buf[4][64];      //  4096 B
    __shared__ float  oarea[4][QH][DD];  // 20480 B
    __shared__ float  mlarea[4][QH][2];  //   640 B

    int blk = blockIdx.x;
    int qh  = blk >> 8;                  // 0/1 query half
    int cc2 = blk & 255;
    int c   = cc2 & (NCH - 1);
    int bh  = cc2 >> 3;
    int h = bh & (HH - 1), b = bh >> 3;
    int t = threadIdx.x, lane = t & 63, w = t >> 6;
    int u0 = qh * QH;

    for (int i = t; i < QH * DD; i += 256) {
        int u = i >> 6, d = i & 63;
        int lq = topi[bh * NT + u0 + u];
        qs[u][d] = Q[(((size_t)b * LL + lq) * HH + h) * DD + d];
    }

    int key = c * CH + w * 64 + lane;
    const float4* kr = (const float4*)&K[(((size_t)b * LL + key) * HH + h) * DD];
    float4 kreg[16];
    #pragma unroll
    for (int j = 0; j < 16; ++j) kreg[j] = kr[j];

    float vcol[64];
    const float* vb = &V[(((size_t)b * LL + c * CH + w * 64) * HH + h) * DD + lane];
    #pragma unroll
    for (int j = 0; j < 64; ++j) vcol[j] = vb[(size_t)j * HH * DD];

    __syncthreads();   // qs ready

    for (int uq = 0; uq < QH / 4; ++uq) {
        float o0 = 0, o1 = 0, o2 = 0, o3 = 0;
        float mv0, mv1, mv2, mv3, lv0, lv1, lv2, lv3;
        float4 ev;
        #pragma unroll
        for (int j = 0; j < 4; ++j) {
            int u = uq * 4 + j;
            const float4* q4 = (const float4*)&qs[u][0];
            float s = 0.0f;
            #pragma unroll
            for (int cc = 0; cc < 16; ++cc) {
                float4 qv = q4[cc];
                s += qv.x * kreg[cc].x + qv.y * kreg[cc].y
                   + qv.z * kreg[cc].z + qv.w * kreg[cc].w;
            }
            s *= 0.125f;   // 1/sqrt(64)
            float m = s;
            #pragma unroll
            for (int off = 32; off >= 1; off >>= 1)
                m = fmaxf(m, __shfl_xor(m, off, 64));
            float e = __expf(s - m);
            float ls = e;
            #pragma unroll
            for (int off = 32; off >= 1; off >>= 1)
                ls += __shfl_xor(ls, off, 64);
            if (j == 0) { mv0 = m; lv0 = ls; ev.x = e; }
            if (j == 1) { mv1 = m; lv1 = ls; ev.y = e; }
            if (j == 2) { mv2 = m; lv2 = ls; ev.z = e; }
            if (j == 3) { mv3 = m; lv3 = ls; ev.w = e; }
        }
        e4buf[w][lane] = ev;
        asm volatile("s_waitcnt lgkmcnt(0)" ::: "memory");
        #pragma unroll
        for (int l2 = 0; l2 < 64; ++l2) {      // FULL unroll: vcol static
            float4 e = e4buf[w][l2];
            float  v = vcol[l2];
            o0 += e.x * v; o1 += e.y * v; o2 += e.z * v; o3 += e.w * v;
        }
        oarea[w][uq * 4 + 0][lane] = o0;
        oarea[w][uq * 4 + 1][lane] = o1;
        oarea[w][uq * 4 + 2][lane] = o2;
        oarea[w][uq * 4 + 3][lane] = o3;
        if (lane == 0) {
            mlarea[w][uq * 4 + 0][0] = mv0; mlarea[w][uq * 4 + 0][1] = lv0;
            mlarea[w][uq * 4 + 1][0] = mv1; mlarea[w][uq * 4 + 1][1] = lv1;
            mlarea[w][uq * 4 + 2][0] = mv2; mlarea[w][uq * 4 + 2][1] = lv2;
            mlarea[w][uq * 4 + 3][0] = mv3; mlarea[w][uq * 4 + 3][1] = lv3;
        }
    }
    __syncthreads();

    for (int i = t; i < QH * DD; i += 256) {
        int u = i >> 6, d = i & 63;
        float m0 = mlarea[0][u][0], m1 = mlarea[1][u][0];
        float m2 = mlarea[2][u][0], m3 = mlarea[3][u][0];
        float mb = fmaxf(fmaxf(m0, m1), fmaxf(m2, m3));
        float s0 = __expf(m0 - mb), s1 = __expf(m1 - mb);
        float s2 = __expf(m2 - mb), s3 = __expf(m3 - mb);
        float ob = oarea[0][u][d] * s0 + oarea[1][u][d] * s1
                 + oarea[2][u][d] * s2 + oarea[3][u][d] * s3;
        int gu = u0 + u;
        po[((size_t)(bh * NT + gu) * NCH + c) * DD + d] = ob;
        if (d == 0) {
            float lb = mlarea[0][u][1] * s0 + mlarea[1][u][1] * s1
                     + mlarea[2][u][1] * s2 + mlarea[3][u][1] * s3;
            pml[(bh * NT + gu) * NCH + c] = make_float2(mb, lb);
        }
    }
}

// ---------------------------------------------------------------------------
// Kernel 4: merge chunk partials. One wave per (bh,u), lane = d.
// ---------------------------------------------------------------------------
__global__ __launch_bounds__(256) void merge_kernel(
        const float2* __restrict__ pml, const float* __restrict__ po,
        float* __restrict__ out) {
    int wid  = blockIdx.x * 4 + (threadIdx.x >> 6);
    int lane = threadIdx.x & 63;
    int u  = wid % NT;
    int bh = wid / NT;
    int h = bh & (HH - 1), b = bh >> 3;
    int base = (bh * NT + u) * NCH;

    float m = -INFINITY;
    #pragma unroll
    for (int cc = 0; cc < NCH; ++cc) m = fmaxf(m, pml[base + cc].x);
    float lsum = 0.0f, o = 0.0f;
    #pragma unroll
    for (int cc = 0; cc < NCH; ++cc) {
        float2 ml = pml[base + cc];
        float sc = __expf(ml.x - m);
        lsum += ml.y * sc;
        o    += po[(size_t)(base + cc) * DD + lane] * sc;
    }
    out[(((size_t)b * NT + u) * HH + h) * DD + lane] = o / lsum;
}

extern "C" void kernel_launch(void* const* d_in, const int* in_sizes, int n_in,
                              void* d_out, int out_size, void* d_ws, size_t ws_size,
                              hipStream_t stream) {
    const float* Q   = (const float*)d_in[0];
    const float* K   = (const float*)d_in[1];
    const float* V   = (const float*)d_in[2];
    const int*   idx = (const int*)d_in[3];
    float* out = (float*)d_out;

    char* ws = (char*)d_ws;
    float*  M    = (float*)ws;                        ws += (size_t)BB * HH * LL * sizeof(float);
    int*    topi = (int*)ws;                          ws += (size_t)BB * HH * NT * sizeof(int);
    float2* pml  = (float2*)ws;                       ws += (size_t)BB * HH * NT * NCH * sizeof(float2);
    float*  po   = (float*)ws;                        // 2.62 MB

    hipLaunchKernelGGL(compute_m_kernel, dim3(BB * LL / 4), dim3(256), 0, stream,
                       Q, K, idx, M);
    hipLaunchKernelGGL(topk_kernel, dim3(BB * HH), dim3(256), 0, stream, M, topi);
    hipLaunchKernelGGL(attn_kernel, dim3(2 * BB * HH * NCH), dim3(256), 0, stream,
                       Q, K, V, topi, pml, po);
    hipLaunchKernelGGL(merge_kernel, dim3(BB * HH * NT / 4), dim3(256), 0, stream,
                       pml, po, out);
}

// Round 14
// 174.880 us; speedup vs baseline: 1.1596x; 1.1596x over previous
//
#include <hip/hip_runtime.h>
#include <hip/hip_bf16.h>

// Problem constants: B=4, L=2048, H=8, D=64, SAMPLE_K=N_TOP=40
#define BB 4
#define LL 2048
#define HH 8
#define DD 64
#define SK 40
#define NT 40
#define CH 256              // keys per attn chunk
#define NCH (LL / CH)       // 8 chunks per (b,h)
#define QH 20               // queries per attn block (40 split in 2)

#define WS 10               // samples per wave (4 waves x 10 = 40)

typedef float f4 __attribute__((ext_vector_type(4)));

// ---------------------------------------------------------------------------
// Kernel 1 (BEST-KNOWN, round-20 config, 165.88us total): whole-wave-per-row,
// depth-6 rolling pipeline, vmcnt(10) steady. One K row (2KB) = 64 lanes x
// 32B = 2 coalesced dwordx4. Lane's floats [lane*8,+8) are head lane>>3,
// dims 8*(lane&7)..+7 — Q's fragment at the SAME offset (identity map).
// Per sample: 8 FMAs + 3 shfl_xor (8-lane head groups). ~41.5us, clean
// counters (WRITE <1MB). Rounds 21-26 (deeper pipelines, saddr, half-row
// L2 phasing) all either matched 42 (L3-BW floor: 655MB gather @ ~15.6TB/s)
// or regressed via opaque 80-170MB scratch/write pathologies. FROZEN.
// ---------------------------------------------------------------------------
__global__ __launch_bounds__(256, 6) void compute_m_kernel(
        const float* __restrict__ Q, const float* __restrict__ K,
        const int* __restrict__ idx, float* __restrict__ M) {
    __shared__ float2 mlpart[4][HH];

    int blk = blockIdx.x;
    int x = blk & 7, g = blk >> 3;
    int b = x >> 1;                    // XCD pair -> batch (per-batch K ~4.2MB)
    int l = (g << 1) | (x & 1);
    int t = threadIdx.x;
    int lane = t & 63, w = t >> 6;
    int grp  = lane >> 3;              // head this lane contributes to

    // Q fragment: same identity map as K rows — floats [lane*8, +8) of row l
    const float* Qrow = Q + ((size_t)b * LL + l) * 512 + lane * 8;
    f4 qa = *(const f4*)(Qrow);
    f4 qb = *(const f4*)(Qrow + 4);

    const float* Kb = K + (size_t)b * LL * 512 + lane * 8;
    const int* ib = idx + (size_t)l * SK + w * WS;

    int i0 = ib[0], i1 = ib[1], i2 = ib[2], i3 = ib[3], i4 = ib[4];
    int i5 = ib[5], i6 = ib[6], i7 = ib[7], i8 = ib[8], i9 = ib[9];
    const float* a0 = Kb + (size_t)i0 * 512;
    const float* a1 = Kb + (size_t)i1 * 512;
    const float* a2 = Kb + (size_t)i2 * 512;
    const float* a3 = Kb + (size_t)i3 * 512;
    const float* a4 = Kb + (size_t)i4 * 512;
    const float* a5 = Kb + (size_t)i5 * 512;
    const float* a6 = Kb + (size_t)i6 * 512;
    const float* a7 = Kb + (size_t)i7 * 512;
    const float* a8 = Kb + (size_t)i8 * 512;
    const float* a9 = Kb + (size_t)i9 * 512;

    // Drain compiler-tracked loads (Q, idx) BEFORE the asm pipeline so the
    // compiler's own vmcnt waits land here, not mid-pipeline.
    asm volatile("" : "+v"(qa), "+v"(qb));

    f4 A0, B0, A1, B1, A2, B2, A3, B3, A4, B4;
    f4 A5, B5, A6, B6, A7, B7, A8, B8, A9, B9;

    // One row = two coalesced dwordx4 (wave covers the full 2KB row).
    #define ISSUE(AV, BV, PTR)                                                  \
        asm volatile("global_load_dwordx4 %0, %2, off\n"                        \
                     "global_load_dwordx4 %1, %2, off offset:16"                \
                     : "=&v"(AV), "=&v"(BV) : "v"(PTR))

    float mx = -INFINITY, sm = 0.0f;

    #define CONS(AV, BV, WAIT) do {                                            \
        asm volatile(WAIT : "+v"(AV), "+v"(BV));                               \
        float p = qa.x*AV.x + qa.y*AV.y + qa.z*AV.z + qa.w*AV.w                \
                + qb.x*BV.x + qb.y*BV.y + qb.z*BV.z + qb.w*BV.w;               \
        p += __shfl_xor(p, 1, 64);                                             \
        p += __shfl_xor(p, 2, 64);                                             \
        p += __shfl_xor(p, 4, 64);                                             \
        mx = fmaxf(mx, p);                                                     \
        sm += p;                                                               \
    } while (0)

    ISSUE(A0, B0, a0); ISSUE(A1, B1, a1); ISSUE(A2, B2, a2);
    ISSUE(A3, B3, a3); ISSUE(A4, B4, a4);
    ISSUE(A5, B5, a5); CONS(A0, B0, "s_waitcnt vmcnt(10)");
    ISSUE(A6, B6, a6); CONS(A1, B1, "s_waitcnt vmcnt(10)");
    ISSUE(A7, B7, a7); CONS(A2, B2, "s_waitcnt vmcnt(10)");
    ISSUE(A8, B8, a8); CONS(A3, B3, "s_waitcnt vmcnt(10)");
    ISSUE(A9, B9, a9); CONS(A4, B4, "s_waitcnt vmcnt(10)");
    CONS(A5, B5, "s_waitcnt vmcnt(8)");
    CONS(A6, B6, "s_waitcnt vmcnt(6)");
    CONS(A7, B7, "s_waitcnt vmcnt(4)");
    CONS(A8, B8, "s_waitcnt vmcnt(2)");
    CONS(A9, B9, "s_waitcnt vmcnt(0)");
    #undef ISSUE
    #undef CONS

    // 8 lanes per wave (one per head group) hold that head's (mx, sm)
    if ((lane & 7) == 0)
        mlpart[w][grp] = make_float2(mx, sm);
    __syncthreads();

    if (t < HH) {
        float MX = -INFINITY, SM = 0.0f;
        #pragma unroll
        for (int w2 = 0; w2 < 4; ++w2) {
            float2 ml = mlpart[w2][t];
            MX = fmaxf(MX, ml.x);
            SM += ml.y;
        }
        M[((size_t)b * HH + t) * LL + l] = MX - SM * (1.0f / (float)LL);
    }
}

// ---------------------------------------------------------------------------
// Kernel 2: top-40 per (b,h), lower index wins ties. Round 27 rewrite:
// BARRIER-FREE parallel extraction. Old version: 40 serial iterations x
// 2 block barriers + single-thread merge (~10-16us on 32 CUs). New: each
// wave extracts top-40 of ITS 512-element segment with wave-local shfl_xor
// argmax only (4 waves parallel, zero barriers; union of per-wave top-40s
// necessarily contains the global top-40). ONE barrier, then wave 0 selects
// the global top-40 from the 160 candidates, again barrier-free. Key packing
// identical ((flip-bits<<11) | (2047-i)) -> ordering/ties bit-identical.
// ---------------------------------------------------------------------------
__global__ __launch_bounds__(256) void topk_kernel(const float* __restrict__ M,
                                                   int* __restrict__ topi) {
    __shared__ unsigned long long cand[192];   // 4 waves x 40 + 32 zero pad
    int bh = blockIdx.x;
    int t  = threadIdx.x;
    int lane = t & 63, w = t >> 6;

    unsigned long long kr[8];
    #pragma unroll
    for (int j = 0; j < 8; ++j) {
        int i = w * 512 + j * 64 + lane;       // coalesced within wave
        unsigned int bits = __float_as_uint(M[(size_t)bh * LL + i]);
        bits = (bits & 0x80000000u) ? ~bits : (bits | 0x80000000u);
        kr[j] = ((unsigned long long)bits << 11)
              | (unsigned int)(LL - 1 - i);
    }
    if (t < 32) cand[160 + t] = 0ULL;          // pad (never selected)

    // wave-local top-40 of this wave's 512 elements (no barriers)
    for (int u = 0; u < NT; ++u) {
        unsigned long long m = kr[0];
        #pragma unroll
        for (int j = 1; j < 8; ++j) if (kr[j] > m) m = kr[j];
        #pragma unroll
        for (int off = 32; off >= 1; off >>= 1) {
            unsigned long long o = __shfl_xor(m, off, 64);
            if (o > m) m = o;
        }
        if (lane == 0) cand[w * NT + u] = m;
        #pragma unroll
        for (int j = 0; j < 8; ++j) if (kr[j] == m) kr[j] = 0ULL;  // unique keys
    }
    __syncthreads();

    // wave 0: global top-40 from 160 candidates (3 per lane, padded to 192)
    if (w == 0) {
        unsigned long long c0 = cand[lane];
        unsigned long long c1 = cand[64 + lane];
        unsigned long long c2 = cand[128 + lane];
        for (int u = 0; u < NT; ++u) {
            unsigned long long m = c0;
            if (c1 > m) m = c1;
            if (c2 > m) m = c2;
            #pragma unroll
            for (int off = 32; off >= 1; off >>= 1) {
                unsigned long long o = __shfl_xor(m, off, 64);
                if (o > m) m = o;
            }
            if (lane == 0) topi[bh * NT + u] = (LL - 1) - (int)(m & 0x7FF);
            if (c0 == m) c0 = 0ULL;
            if (c1 == m) c1 = 0ULL;
            if (c2 == m) c2 = 0ULL;
        }
    }
}

// ---------------------------------------------------------------------------
// Kernel 3: flash-chunked attention, query-split.
// __launch_bounds__(256,3) keeps kreg/vcol in registers (round 7 spill fix).
// (m,l) packed float2 store (round 8 granule-waste fix).
// ---------------------------------------------------------------------------
__global__ __launch_bounds__(256, 3) void attn_kernel(
        const float* __restrict__ Q, const float* __restrict__ K,
        const float* __restrict__ V, const int* __restrict__ topi,
        float2* __restrict__ pml, float* __restrict__ po) {
    __shared__ float  qs[QH][DD];        //  5120 B
    __shared__ float4 e4buf[4][64];      //  4096 B
    __shared__ float  oarea[4][QH][DD];  // 20480 B
    __shared__ float  mlarea[4][QH][2];  //   640 B

    int blk = blockIdx.x;
    int qh  = blk >> 8;                  // 0/1 query half
    int cc2 = blk & 255;
    int c   = cc2 & (NCH - 1);
    int bh  = cc2 >> 3;
    int h = bh & (HH - 1), b = bh >> 3;
    int t = threadIdx.x, lane = t & 63, w = t >> 6;
    int u0 = qh * QH;

    for (int i = t; i < QH * DD; i += 256) {
        int u = i >> 6, d = i & 63;
        int lq = topi[bh * NT + u0 + u];
        qs[u][d] = Q[(((size_t)b * LL + lq) * HH + h) * DD + d];
    }

    int key = c * CH + w * 64 + lane;
    const float4* kr = (const float4*)&K[(((size_t)b * LL + key) * HH + h) * DD];
    float4 kreg[16];
    #pragma unroll
    for (int j = 0; j < 16; ++j) kreg[j] = kr[j];

    float vcol[64];
    const float* vb = &V[(((size_t)b * LL + c * CH + w * 64) * HH + h) * DD + lane];
    #pragma unroll
    for (int j = 0; j < 64; ++j) vcol[j] = vb[(size_t)j * HH * DD];

    __syncthreads();   // qs ready

    for (int uq = 0; uq < QH / 4; ++uq) {
        float o0 = 0, o1 = 0, o2 = 0, o3 = 0;
        float mv0, mv1, mv2, mv3, lv0, lv1, lv2, lv3;
        float4 ev;
        #pragma unroll
        for (int j = 0; j < 4; ++j) {
            int u = uq * 4 + j;
            const float4* q4 = (const float4*)&qs[u][0];
            float s = 0.0f;
            #pragma unroll
            for (int cc = 0; cc < 16; ++cc) {
                float4 qv = q4[cc];
                s += qv.x * kreg[cc].x + qv.y * kreg[cc].y
                   + qv.z * kreg[cc].z + qv.w * kreg[cc].w;
            }
            s *= 0.125f;   // 1/sqrt(64)
            float m = s;
            #pragma unroll
            for (int off = 32; off >= 1; off >>= 1)
                m = fmaxf(m, __shfl_xor(m, off, 64));
            float e = __expf(s - m);
            float ls = e;
            #pragma unroll
            for (int off = 32; off >= 1; off >>= 1)
                ls += __shfl_xor(ls, off, 64);
            if (j == 0) { mv0 = m; lv0 = ls; ev.x = e; }
            if (j == 1) { mv1 = m; lv1 = ls; ev.y = e; }
            if (j == 2) { mv2 = m; lv2 = ls; ev.z = e; }
            if (j == 3) { mv3 = m; lv3 = ls; ev.w = e; }
        }
        e4buf[w][lane] = ev;
        asm volatile("s_waitcnt lgkmcnt(0)" ::: "memory");
        #pragma unroll
        for (int l2 = 0; l2 < 64; ++l2) {      // FULL unroll: vcol static
            float4 e = e4buf[w][l2];
            float  v = vcol[l2];
            o0 += e.x * v; o1 += e.y * v; o2 += e.z * v; o3 += e.w * v;
        }
        oarea[w][uq * 4 + 0][lane] = o0;
        oarea[w][uq * 4 + 1][lane] = o1;
        oarea[w][uq * 4 + 2][lane] = o2;
        oarea[w][uq * 4 + 3][lane] = o3;
        if (lane == 0) {
            mlarea[w][uq * 4 + 0][0] = mv0; mlarea[w][uq * 4 + 0][1] = lv0;
            mlarea[w][uq * 4 + 1][0] = mv1; mlarea[w][uq * 4 + 1][1] = lv1;
            mlarea[w][uq * 4 + 2][0] = mv2; mlarea[w][uq * 4 + 2][1] = lv2;
            mlarea[w][uq * 4 + 3][0] = mv3; mlarea[w][uq * 4 + 3][1] = lv3;
        }
    }
    __syncthreads();

    for (int i = t; i < QH * DD; i += 256) {
        int u = i >> 6, d = i & 63;
        float m0 = mlarea[0][u][0], m1 = mlarea[1][u][0];
        float m2 = mlarea[2][u][0], m3 = mlarea[3][u][0];
        float mb = fmaxf(fmaxf(m0, m1), fmaxf(m2, m3));
        float s0 = __expf(m0 - mb), s1 = __expf(m1 - mb);
        float s2 = __expf(m2 - mb), s3 = __expf(m3 - mb);
        float ob = oarea[0][u][d] * s0 + oarea[1][u][d] * s1
                 + oarea[2][u][d] * s2 + oarea[3][u][d] * s3;
        int gu = u0 + u;
        po[((size_t)(bh * NT + gu) * NCH + c) * DD + d] = ob;
        if (d == 0) {
            float lb = mlarea[0][u][1] * s0 + mlarea[1][u][1] * s1
                     + mlarea[2][u][1] * s2 + mlarea[3][u][1] * s3;
            pml[(bh * NT + gu) * NCH + c] = make_float2(mb, lb);
        }
    }
}

// ---------------------------------------------------------------------------
// Kernel 4: merge chunk partials. One wave per (bh,u), lane = d.
// ---------------------------------------------------------------------------
__global__ __launch_bounds__(256) void merge_kernel(
        const float2* __restrict__ pml, const float* __restrict__ po,
        float* __restrict__ out) {
    int wid  = blockIdx.x * 4 + (threadIdx.x >> 6);
    int lane = threadIdx.x & 63;
    int u  = wid % NT;
    int bh = wid / NT;
    int h = bh & (HH - 1), b = bh >> 3;
    int base = (bh * NT + u) * NCH;

    float m = -INFINITY;
    #pragma unroll
    for (int cc = 0; cc < NCH; ++cc) m = fmaxf(m, pml[base + cc].x);
    float lsum = 0.0f, o = 0.0f;
    #pragma unroll
    for (int cc = 0; cc < NCH; ++cc) {
        float2 ml = pml[base + cc];
        float sc = __expf(ml.x - m);
        lsum += ml.y * sc;
        o    += po[(size_t)(base + cc) * DD + lane] * sc;
    }
    out[(((size_t)b * NT + u) * HH + h) * DD + lane] = o / lsum;
}

extern "C" void kernel_launch(void* const* d_in, const int* in_sizes, int n_in,
                              void* d_out, int out_size, void* d_ws, size_t ws_size,
                              hipStream_t stream) {
    const float* Q   = (const float*)d_in[0];
    const float* K   = (const float*)d_in[1];
    const float* V   = (const float*)d_in[2];
    const int*   idx = (const int*)d_in[3];
    float* out = (float*)d_out;

    char* ws = (char*)d_ws;
    float*  M    = (float*)ws;                        ws += (size_t)BB * HH * LL * sizeof(float);
    int*    topi = (int*)ws;                          ws += (size_t)BB * HH * NT * sizeof(int);
    float2* pml  = (float2*)ws;                       ws += (size_t)BB * HH * NT * NCH * sizeof(float2);
    float*  po   = (float*)ws;                        // 2.62 MB

    hipLaunchKernelGGL(compute_m_kernel, dim3(BB * LL), dim3(256), 0, stream,
                       Q, K, idx, M);
    hipLaunchKernelGGL(topk_kernel, dim3(BB * HH), dim3(256), 0, stream, M, topi);
    hipLaunchKernelGGL(attn_kernel, dim3(2 * BB * HH * NCH), dim3(256), 0, stream,
                       Q, K, V, topi, pml, po);
    hipLaunchKernelGGL(merge_kernel, dim3(BB * HH * NT / 4), dim3(256), 0, stream,
                       pml, po, out);
}

// Round 15
// 167.228 us; speedup vs baseline: 1.2126x; 1.0458x over previous
//
#include <hip/hip_runtime.h>
#include <hip/hip_bf16.h>

// Problem constants: B=4, L=2048, H=8, D=64, SAMPLE_K=N_TOP=40
#define BB 4
#define LL 2048
#define HH 8
#define DD 64
#define SK 40
#define NT 40
#define CH 256              // keys per attn chunk
#define NCH (LL / CH)       // 8 chunks per (b,h)
#define QH 20               // queries per attn block (40 split in 2)

#define WS 10               // samples per wave (4 waves x 10 = 40)

typedef float f4 __attribute__((ext_vector_type(4)));

// ---------------------------------------------------------------------------
// Kernel 1 (BEST-KNOWN, round-20 config): whole-wave-per-row, depth-6 rolling
// pipeline, vmcnt(10) steady. One K row (2KB) = 64 lanes x 32B = 2 coalesced
// dwordx4. Lane's floats [lane*8,+8) are head lane>>3, dims 8*(lane&7)..+7 —
// Q's fragment at the SAME offset (identity map). Per sample: 8 FMAs +
// 3 shfl_xor (8-lane head groups). ~41.5us, clean counters (WRITE <1MB).
// Rounds 21-26 (deeper pipelines, saddr, half-row L2 phasing) all either
// matched 42us (L3-BW floor: 655MB gather @ ~15.6TB/s) or regressed via
// scratch/write pathologies. FROZEN at the L3 roofline.
// ---------------------------------------------------------------------------
__global__ __launch_bounds__(256, 6) void compute_m_kernel(
        const float* __restrict__ Q, const float* __restrict__ K,
        const int* __restrict__ idx, float* __restrict__ M) {
    __shared__ float2 mlpart[4][HH];

    int blk = blockIdx.x;
    int x = blk & 7, g = blk >> 3;
    int b = x >> 1;                    // XCD pair -> batch (per-batch K ~4.2MB)
    int l = (g << 1) | (x & 1);
    int t = threadIdx.x;
    int lane = t & 63, w = t >> 6;
    int grp  = lane >> 3;              // head this lane contributes to

    // Q fragment: same identity map as K rows — floats [lane*8, +8) of row l
    const float* Qrow = Q + ((size_t)b * LL + l) * 512 + lane * 8;
    f4 qa = *(const f4*)(Qrow);
    f4 qb = *(const f4*)(Qrow + 4);

    const float* Kb = K + (size_t)b * LL * 512 + lane * 8;
    const int* ib = idx + (size_t)l * SK + w * WS;

    int i0 = ib[0], i1 = ib[1], i2 = ib[2], i3 = ib[3], i4 = ib[4];
    int i5 = ib[5], i6 = ib[6], i7 = ib[7], i8 = ib[8], i9 = ib[9];
    const float* a0 = Kb + (size_t)i0 * 512;
    const float* a1 = Kb + (size_t)i1 * 512;
    const float* a2 = Kb + (size_t)i2 * 512;
    const float* a3 = Kb + (size_t)i3 * 512;
    const float* a4 = Kb + (size_t)i4 * 512;
    const float* a5 = Kb + (size_t)i5 * 512;
    const float* a6 = Kb + (size_t)i6 * 512;
    const float* a7 = Kb + (size_t)i7 * 512;
    const float* a8 = Kb + (size_t)i8 * 512;
    const float* a9 = Kb + (size_t)i9 * 512;

    // Drain compiler-tracked loads (Q, idx) BEFORE the asm pipeline so the
    // compiler's own vmcnt waits land here, not mid-pipeline.
    asm volatile("" : "+v"(qa), "+v"(qb));

    f4 A0, B0, A1, B1, A2, B2, A3, B3, A4, B4;
    f4 A5, B5, A6, B6, A7, B7, A8, B8, A9, B9;

    // One row = two coalesced dwordx4 (wave covers the full 2KB row).
    #define ISSUE(AV, BV, PTR)                                                  \
        asm volatile("global_load_dwordx4 %0, %2, off\n"                        \
                     "global_load_dwordx4 %1, %2, off offset:16"                \
                     : "=&v"(AV), "=&v"(BV) : "v"(PTR))

    float mx = -INFINITY, sm = 0.0f;

    #define CONS(AV, BV, WAIT) do {                                            \
        asm volatile(WAIT : "+v"(AV), "+v"(BV));                               \
        float p = qa.x*AV.x + qa.y*AV.y + qa.z*AV.z + qa.w*AV.w                \
                + qb.x*BV.x + qb.y*BV.y + qb.z*BV.z + qb.w*BV.w;               \
        p += __shfl_xor(p, 1, 64);                                             \
        p += __shfl_xor(p, 2, 64);                                             \
        p += __shfl_xor(p, 4, 64);                                             \
        mx = fmaxf(mx, p);                                                     \
        sm += p;                                                               \
    } while (0)

    ISSUE(A0, B0, a0); ISSUE(A1, B1, a1); ISSUE(A2, B2, a2);
    ISSUE(A3, B3, a3); ISSUE(A4, B4, a4);
    ISSUE(A5, B5, a5); CONS(A0, B0, "s_waitcnt vmcnt(10)");
    ISSUE(A6, B6, a6); CONS(A1, B1, "s_waitcnt vmcnt(10)");
    ISSUE(A7, B7, a7); CONS(A2, B2, "s_waitcnt vmcnt(10)");
    ISSUE(A8, B8, a8); CONS(A3, B3, "s_waitcnt vmcnt(10)");
    ISSUE(A9, B9, a9); CONS(A4, B4, "s_waitcnt vmcnt(10)");
    CONS(A5, B5, "s_waitcnt vmcnt(8)");
    CONS(A6, B6, "s_waitcnt vmcnt(6)");
    CONS(A7, B7, "s_waitcnt vmcnt(4)");
    CONS(A8, B8, "s_waitcnt vmcnt(2)");
    CONS(A9, B9, "s_waitcnt vmcnt(0)");
    #undef ISSUE
    #undef CONS

    // 8 lanes per wave (one per head group) hold that head's (mx, sm)
    if ((lane & 7) == 0)
        mlpart[w][grp] = make_float2(mx, sm);
    __syncthreads();

    if (t < HH) {
        float MX = -INFINITY, SM = 0.0f;
        #pragma unroll
        for (int w2 = 0; w2 < 4; ++w2) {
            float2 ml = mlpart[w2][t];
            MX = fmaxf(MX, ml.x);
            SM += ml.y;
        }
        M[((size_t)b * HH + t) * LL + l] = MX - SM * (1.0f / (float)LL);
    }
}

// ---------------------------------------------------------------------------
// Kernel 2: top-40 per (b,h), lower index wins ties. Incremental argmax.
// (Round-28 note: the barrier-free parallel rewrite measured WORSE — 80
// serial wave-reduce iterations on the critical path vs 40 here. Reverted.)
// ---------------------------------------------------------------------------
__global__ __launch_bounds__(256) void topk_kernel(const float* __restrict__ M,
                                                   int* __restrict__ topi) {
    __shared__ unsigned long long keys[LL];   // 16 KB
    __shared__ unsigned long long wmax[4];
    __shared__ int win;
    int bh = blockIdx.x;
    int t  = threadIdx.x;
    int lane = t & 63, w = t >> 6;

    unsigned long long kmax = 0ULL;
    #pragma unroll
    for (int j = 0; j < 8; ++j) {
        int i = t + 256 * j;
        unsigned int bits = __float_as_uint(M[(size_t)bh * LL + i]);
        bits = (bits & 0x80000000u) ? ~bits : (bits | 0x80000000u);
        unsigned long long k = ((unsigned long long)bits << 11)
                             | (unsigned int)(LL - 1 - i);
        keys[i] = k;
        if (k > kmax) kmax = k;
    }
    __syncthreads();

    for (int u = 0; u < NT; ++u) {
        unsigned long long k = kmax;
        #pragma unroll
        for (int off = 32; off >= 1; off >>= 1) {
            unsigned long long o = __shfl_xor(k, off, 64);
            if (o > k) k = o;
        }
        if (lane == 0) wmax[w] = k;
        __syncthreads();
        if (t == 0) {
            unsigned long long k0 = wmax[0];
            if (wmax[1] > k0) k0 = wmax[1];
            if (wmax[2] > k0) k0 = wmax[2];
            if (wmax[3] > k0) k0 = wmax[3];
            int i = (LL - 1) - (int)(k0 & 0x7FF);
            topi[bh * NT + u] = i;
            keys[i] = 0ULL;
            win = i;
        }
        __syncthreads();
        if ((win & 255) == t) {          // only the owner rescans
            kmax = 0ULL;
            #pragma unroll
            for (int j = 0; j < 8; ++j) {
                unsigned long long kk = keys[t + 256 * j];
                if (kk > kmax) kmax = kk;
            }
        }
    }
}

// ---------------------------------------------------------------------------
// Kernel 3: flash-chunked attention, query-split.
// __launch_bounds__(256,3) keeps kreg/vcol in registers (round 7 spill fix).
// (m,l) packed float2 store (round 8 granule-waste fix).
// ---------------------------------------------------------------------------
__global__ __launch_bounds__(256, 3) void attn_kernel(
        const float* __restrict__ Q, const float* __restrict__ K,
        const float* __restrict__ V, const int* __restrict__ topi,
        float2* __restrict__ pml, float* __restrict__ po) {
    __shared__ float  qs[QH][DD];        //  5120 B
    __shared__ float4 e4buf[4][64];      //  4096 B
    __shared__ float  oarea[4][QH][DD];  // 20480 B
    __shared__ float  mlarea[4][QH][2];  //   640 B

    int blk = blockIdx.x;
    int qh  = blk >> 8;                  // 0/1 query half
    int cc2 = blk & 255;
    int c   = cc2 & (NCH - 1);
    int bh  = cc2 >> 3;
    int h = bh & (HH - 1), b = bh >> 3;
    int t = threadIdx.x, lane = t & 63, w = t >> 6;
    int u0 = qh * QH;

    for (int i = t; i < QH * DD; i += 256) {
        int u = i >> 6, d = i & 63;
        int lq = topi[bh * NT + u0 + u];
        qs[u][d] = Q[(((size_t)b * LL + lq) * HH + h) * DD + d];
    }

    int key = c * CH + w * 64 + lane;
    const float4* kr = (const float4*)&K[(((size_t)b * LL + key) * HH + h) * DD];
    float4 kreg[16];
    #pragma unroll
    for (int j = 0; j < 16; ++j) kreg[j] = kr[j];

    float vcol[64];
    const float* vb = &V[(((size_t)b * LL + c * CH + w * 64) * HH + h) * DD + lane];
    #pragma unroll
    for (int j = 0; j < 64; ++j) vcol[j] = vb[(size_t)j * HH * DD];

    __syncthreads();   // qs ready

    for (int uq = 0; uq < QH / 4; ++uq) {
        float o0 = 0, o1 = 0, o2 = 0, o3 = 0;
        float mv0, mv1, mv2, mv3, lv0, lv1, lv2, lv3;
        float4 ev;
        #pragma unroll
        for (int j = 0; j < 4; ++j) {
            int u = uq * 4 + j;
            const float4* q4 = (const float4*)&qs[u][0];
            float s = 0.0f;
            #pragma unroll
            for (int cc = 0; cc < 16; ++cc) {
                float4 qv = q4[cc];
                s += qv.x * kreg[cc].x + qv.y * kreg[cc].y
                   + qv.z * kreg[cc].z + qv.w * kreg[cc].w;
            }
            s *= 0.125f;   // 1/sqrt(64)
            float m = s;
            #pragma unroll
            for (int off = 32; off >= 1; off >>= 1)
                m = fmaxf(m, __shfl_xor(m, off, 64));
            float e = __expf(s - m);
            float ls = e;
            #pragma unroll
            for (int off = 32; off >= 1; off >>= 1)
                ls += __shfl_xor(ls, off, 64);
            if (j == 0) { mv0 = m; lv0 = ls; ev.x = e; }
            if (j == 1) { mv1 = m; lv1 = ls; ev.y = e; }
            if (j == 2) { mv2 = m; lv2 = ls; ev.z = e; }
            if (j == 3) { mv3 = m; lv3 = ls; ev.w = e; }
        }
        e4buf[w][lane] = ev;
        asm volatile("s_waitcnt lgkmcnt(0)" ::: "memory");
        #pragma unroll
        for (int l2 = 0; l2 < 64; ++l2) {      // FULL unroll: vcol static
            float4 e = e4buf[w][l2];
            float  v = vcol[l2];
            o0 += e.x * v; o1 += e.y * v; o2 += e.z * v; o3 += e.w * v;
        }
        oarea[w][uq * 4 + 0][lane] = o0;
        oarea[w][uq * 4 + 1][lane] = o1;
        oarea[w][uq * 4 + 2][lane] = o2;
        oarea[w][uq * 4 + 3][lane] = o3;
        if (lane == 0) {
            mlarea[w][uq * 4 + 0][0] = mv0; mlarea[w][uq * 4 + 0][1] = lv0;
            mlarea[w][uq * 4 + 1][0] = mv1; mlarea[w][uq * 4 + 1][1] = lv1;
            mlarea[w][uq * 4 + 2][0] = mv2; mlarea[w][uq * 4 + 2][1] = lv2;
            mlarea[w][uq * 4 + 3][0] = mv3; mlarea[w][uq * 4 + 3][1] = lv3;
        }
    }
    __syncthreads();

    for (int i = t; i < QH * DD; i += 256) {
        int u = i >> 6, d = i & 63;
        float m0 = mlarea[0][u][0], m1 = mlarea[1][u][0];
        float m2 = mlarea[2][u][0], m3 = mlarea[3][u][0];
        float mb = fmaxf(fmaxf(m0, m1), fmaxf(m2, m3));
        float s0 = __expf(m0 - mb), s1 = __expf(m1 - mb);
        float s2 = __expf(m2 - mb), s3 = __expf(m3 - mb);
        float ob = oarea[0][u][d] * s0 + oarea[1][u][d] * s1
                 + oarea[2][u][d] * s2 + oarea[3][u][d] * s3;
        int gu = u0 + u;
        po[((size_t)(bh * NT + gu) * NCH + c) * DD + d] = ob;
        if (d == 0) {
            float lb = mlarea[0][u][1] * s0 + mlarea[1][u][1] * s1
                     + mlarea[2][u][1] * s2 + mlarea[3][u][1] * s3;
            pml[(bh * NT + gu) * NCH + c] = make_float2(mb, lb);
        }
    }
}

// ---------------------------------------------------------------------------
// Kernel 4: merge chunk partials. One wave per (bh,u), lane = d.
// ---------------------------------------------------------------------------
__global__ __launch_bounds__(256) void merge_kernel(
        const float2* __restrict__ pml, const float* __restrict__ po,
        float* __restrict__ out) {
    int wid  = blockIdx.x * 4 + (threadIdx.x >> 6);
    int lane = threadIdx.x & 63;
    int u  = wid % NT;
    int bh = wid / NT;
    int h = bh & (HH - 1), b = bh >> 3;
    int base = (bh * NT + u) * NCH;

    float m = -INFINITY;
    #pragma unroll
    for (int cc = 0; cc < NCH; ++cc) m = fmaxf(m, pml[base + cc].x);
    float lsum = 0.0f, o = 0.0f;
    #pragma unroll
    for (int cc = 0; cc < NCH; ++cc) {
        float2 ml = pml[base + cc];
        float sc = __expf(ml.x - m);
        lsum += ml.y * sc;
        o    += po[(size_t)(base + cc) * DD + lane] * sc;
    }
    out[(((size_t)b * NT + u) * HH + h) * DD + lane] = o / lsum;
}

extern "C" void kernel_launch(void* const* d_in, const int* in_sizes, int n_in,
                              void* d_out, int out_size, void* d_ws, size_t ws_size,
                              hipStream_t stream) {
    const float* Q   = (const float*)d_in[0];
    const float* K   = (const float*)d_in[1];
    const float* V   = (const float*)d_in[2];
    const int*   idx = (const int*)d_in[3];
    float* out = (float*)d_out;

    char* ws = (char*)d_ws;
    float*  M    = (float*)ws;                        ws += (size_t)BB * HH * LL * sizeof(float);
    int*    topi = (int*)ws;                          ws += (size_t)BB * HH * NT * sizeof(int);
    float2* pml  = (float2*)ws;                       ws += (size_t)BB * HH * NT * NCH * sizeof(float2);
    float*  po   = (float*)ws;                        // 2.62 MB

    hipLaunchKernelGGL(compute_m_kernel, dim3(BB * LL), dim3(256), 0, stream,
                       Q, K, idx, M);
    hipLaunchKernelGGL(topk_kernel, dim3(BB * HH), dim3(256), 0, stream, M, topi);
    hipLaunchKernelGGL(attn_kernel, dim3(2 * BB * HH * NCH), dim3(256), 0, stream,
                       Q, K, V, topi, pml, po);
    hipLaunchKernelGGL(merge_kernel, dim3(BB * HH * NT / 4), dim3(256), 0, stream,
                       pml, po, out);
}